// Round 5
// baseline (1406.370 us; speedup 1.0000x reference)
//
#include <hip/hip_runtime.h>

#define BATCH 8
#define NPTS 8192
#define NCH 64
#define NPOINT 1024
#define NSAMPLE 32
#define G 16    // groups per MLP block
#define SUBS 8  // FPS blocks per batch

typedef float f4 __attribute__((ext_vector_type(4)));
typedef float f2 __attribute__((ext_vector_type(2)));
typedef _Float16 h8 __attribute__((ext_vector_type(8)));

// DPP-based u64 max step: merge with the value DPP-shifted across lanes.
template <int CTRL>
__device__ __forceinline__ unsigned long long dpp_max_u64(unsigned long long k) {
  int lo = (int)(unsigned int)k;
  int hi = (int)(unsigned int)(k >> 32);
  int slo = __builtin_amdgcn_update_dpp(lo, lo, CTRL, 0xf, 0xf, false);
  int shi = __builtin_amdgcn_update_dpp(hi, hi, CTRL, 0xf, 0xf, false);
  unsigned long long s =
      ((unsigned long long)(unsigned int)shi << 32) | (unsigned int)slo;
  return (s > k) ? s : k;
}

// ---------------------------------------------------------------------------
// Furthest point sampling — R16: multi-CU. R12-R15 established the 1-block/
// batch design is pinned at ~2330 cyc/iter: ~60% VALU-issue on 4 SIMDs (R3:
// same per-SIMD issue at 2 waves -> no change; R15: +70 instr -> +7%), rest
// barrier/LDS/DPP tail. Only structural fix: spread the 8192-pt distance
// update over 8 CUs/batch. 64 blocks x 64 thr (1 wave each, no intra-block
// barrier): block = (batch = bid&7, sub = bid>>3) owns points
// [sub*1024, sub*1024+1024), 8 f2 slots/lane. Same exact fp32 arithmetic,
// same serial scan, same u64 DPP wave reduce. Cross-block: lane63 publishes
// the block key as ONE relaxed device-scope u64 atomic store into
// rec[batch][i&1][sub]; key low word = (i<<13)|(~gidx&0x1FFF) so the
// iteration tag is self-validating (tag bits equal within an iteration ->
// u64 max still orders by mind then lowest gidx == ref tie-break). No
// fences. Parity slots make overwrite-before-read impossible (publish of
// i+2 requires completed gather of i+1, which requires all blocks gathered
// i). rec lives in d_ws[0..1KB) — free until ball_kernel runs — zeroed by
// capture-safe hipMemsetAsync. Co-residency: 64 blocks, 98KB LDS -> 1
// block/CU on 256 CUs, all resident -> deadlock-free.
// Pivot coords + final output from the per-block full LDS copy (96KB).
// Predict fps 921 -> ~470-650 us; Occupancy 0.38 -> ~0.75.
// ---------------------------------------------------------------------------
__global__ __launch_bounds__(64, 1) void fps_kernel(
    const float* __restrict__ xyz, float* __restrict__ newxyz,
    unsigned long long* __restrict__ rec) {
  const int bid = blockIdx.x;
  const int batch = bid & 7;  // same-batch blocks share an XCD under rr map
  const int sub = bid >> 3;   // 0..7
  const int lane = threadIdx.x;  // 0..63
  const float* xb = xyz + (size_t)batch * NPTS * 3;
  unsigned long long* rb = rec + batch * (2 * SUBS);

  __shared__ float px_l[NPTS], py_l[NPTS], pz_l[NPTS];  // 96 KB SoA
  __shared__ unsigned short winidx[NPOINT];             // used by sub 0

  // stage full point set (pivot fetch + output need random access)
  for (int p = lane; p < NPTS; p += 64) {
    px_l[p] = xb[p * 3 + 0];
    py_l[p] = xb[p * 3 + 1];
    pz_l[p] = xb[p * 3 + 2];
  }
  __syncthreads();

  // register fill: this block's 1024 points, slot j -> pair at
  // base + 2*lane + 128*j
  const int base = sub * 1024;
  f2 pxv[8], pyv[8], pzv[8], mindv[8];
#pragma unroll
  for (int j = 0; j < 8; ++j) {
    int p = base + 2 * lane + 128 * j;
    pxv[j] = *(const f2*)&px_l[p];
    pyv[j] = *(const f2*)&py_l[p];
    pzv[j] = *(const f2*)&pz_l[p];
    mindv[j] = f2{1e10f, 1e10f};
  }
#pragma unroll
  for (int j = 0; j < 8; ++j) {
    asm volatile("" : "+v"(pxv[j]), "+v"(pyv[j]), "+v"(pzv[j]));
  }
  float qx = px_l[0], qy = py_l[0], qz = pz_l[0];  // pivot = point 0

  for (int i = 1; i < NPOINT; ++i) {
#pragma clang fp contract(off)
    f2 qx2 = f2{qx, qx}, qy2 = f2{qy, qy}, qz2 = f2{qz, qz};

    // distance update (exact ref order) + value-only max tree
    f2 tmax;
#pragma unroll
    for (int j = 0; j < 8; ++j) {
      f2 dx = pxv[j] - qx2;
      f2 dy = pyv[j] - qy2;
      f2 dz = pzv[j] - qz2;
      f2 d = (dx * dx + dy * dy) + dz * dz;
      f2 m = __builtin_elementwise_min(mindv[j], d);
      mindv[j] = m;
      tmax = (j == 0) ? m : __builtin_elementwise_max(tmax, m);
    }
    float lmax = fmaxf(tmax.x, tmax.y);

    // thread-local lowest matching index (proven serial scan form)
    int c = 0;
#pragma unroll
    for (int j = 7; j >= 0; --j) {
      if (mindv[j].y == lmax) c = 2 * j + 1;
      if (mindv[j].x == lmax) c = 2 * j;
    }
    unsigned int gidx =
        (unsigned int)(base + 2 * lane + ((c >> 1) << 7) + (c & 1));
    const unsigned int tagbits = ((unsigned int)i) << 13;
    unsigned int lo = tagbits | ((~gidx) & 0x1FFFu);
    unsigned long long key =
        ((unsigned long long)__float_as_uint(lmax) << 32) |
        (unsigned long long)lo;

    // wave argmax via DPP, result valid in lane 63
    key = dpp_max_u64<0x111>(key);  // row_shr:1
    key = dpp_max_u64<0x112>(key);  // row_shr:2
    key = dpp_max_u64<0x114>(key);  // row_shr:4
    key = dpp_max_u64<0x118>(key);  // row_shr:8
    key = dpp_max_u64<0x142>(key);  // row_bcast:15
    key = dpp_max_u64<0x143>(key);  // row_bcast:31

    unsigned long long* slot = rb + (i & 1) * SUBS;
    if (lane == 63) {
      __hip_atomic_store(&slot[sub], key, __ATOMIC_RELAXED,
                         __HIP_MEMORY_SCOPE_AGENT);
    }

    // poll all 8 block records; keys are self-validating via tag bits
    unsigned long long k[SUBS];
    for (;;) {
      bool ok = true;
#pragma unroll
      for (int s = 0; s < SUBS; ++s) {
        k[s] = __hip_atomic_load(&slot[s], __ATOMIC_RELAXED,
                                 __HIP_MEMORY_SCOPE_AGENT);
      }
#pragma unroll
      for (int s = 0; s < SUBS; ++s) {
        ok &= (((unsigned int)k[s] & 0xFFFFE000u) == tagbits);
      }
      if (ok) break;
      __builtin_amdgcn_s_sleep(1);
    }

    // merge 8 keys: 7 u64 compare-selects
    unsigned long long m01 = (k[0] > k[1]) ? k[0] : k[1];
    unsigned long long m23 = (k[2] > k[3]) ? k[2] : k[3];
    unsigned long long m45 = (k[4] > k[5]) ? k[4] : k[5];
    unsigned long long m67 = (k[6] > k[7]) ? k[6] : k[7];
    unsigned long long m0123 = (m01 > m23) ? m01 : m23;
    unsigned long long m4567 = (m45 > m67) ? m45 : m67;
    unsigned long long mk = (m0123 > m4567) ? m0123 : m4567;
    unsigned int widx = (~(unsigned int)mk) & 0x1FFFu;

    // pivot coords: broadcast ds_read at the winner
    qx = px_l[widx];
    qy = py_l[widx];
    qz = pz_l[widx];
    if (sub == 0 && lane == 0) winidx[i] = (unsigned short)widx;
  }

  __syncthreads();
  if (sub == 0) {
    for (int t = lane; t < NPOINT; t += 64) {
      const int idx = (t == 0) ? 0 : (int)winidx[t];
      float* op = newxyz + batch * (NPOINT * 3) + t * 3;
      op[0] = px_l[idx];
      op[1] = py_l[idx];
      op[2] = pz_l[idx];
    }
  }
}

// ---------------------------------------------------------------------------
// Ball query: one wave per (b, s) center. Unchanged (exact fp32).
// ---------------------------------------------------------------------------
__global__ __launch_bounds__(256) void ball_kernel(const float* __restrict__ xyz,
                                                   const float* __restrict__ newxyz,
                                                   int* __restrict__ idxout) {
  const int lane = threadIdx.x & 63;
  const int pair = blockIdx.x * 4 + (threadIdx.x >> 6);
  const int b = pair >> 10;
  const float cx = newxyz[pair * 3 + 0];
  const float cy = newxyz[pair * 3 + 1];
  const float cz = newxyz[pair * 3 + 2];
  const float* xb = xyz + (size_t)b * NPTS * 3;
  int* op = idxout + pair * NSAMPLE;

  int cnt = 0;
  int first = 0;
  for (int base = 0; base < NPTS && cnt < NSAMPLE; base += 64) {
    const int p = base + lane;
    const float* pp = xb + p * 3;
    float dx = __fsub_rn(cx, pp[0]);
    float dy = __fsub_rn(cy, pp[1]);
    float dz = __fsub_rn(cz, pp[2]);
    float d2 = __fadd_rn(__fadd_rn(__fmul_rn(dx, dx), __fmul_rn(dy, dy)),
                         __fmul_rn(dz, dz));
    bool pred = d2 < 0.04f;
    unsigned long long m = __ballot(pred);
    if (cnt == 0 && m) first = base + __builtin_ctzll(m);
    int rank = cnt + (int)__popcll(m & ((1ull << lane) - 1ull));
    if (pred && rank < NSAMPLE) op[rank] = p;
    cnt += (int)__popcll(m);
  }
  if (cnt < NSAMPLE) {
    for (int r = cnt + lane; r < NSAMPLE; r += 64) op[r] = first;
  }
}

// ---------------------------------------------------------------------------
// Group + 3-layer MLP + max-pool via f16 MFMA. G=16 groups/block, grid 512.
// Unchanged from R10 (weights register-resident as B-fragments, layouts
// HW-verified m89/m120, fp32 accumulate; absmax 0.0156 < 0.054).
// ---------------------------------------------------------------------------
__global__ __launch_bounds__(256) void group_mlp_kernel(
    const float* __restrict__ xyz, const float* __restrict__ feat,
    const float* __restrict__ w0, const float* __restrict__ s0, const float* __restrict__ b0,
    const float* __restrict__ w1, const float* __restrict__ s1, const float* __restrict__ b1,
    const float* __restrict__ w2, const float* __restrict__ s2, const float* __restrict__ b2,
    const int* __restrict__ idxin, const float* __restrict__ newxyz,
    float* __restrict__ outf) {
  __shared__ _Float16 x0[32 * 104];  // layer1 input, K-padded to 96
  __shared__ _Float16 x1[32 * 72];   // layer2 input
  __shared__ _Float16 x2[32 * 72];   // layer3 input
  __shared__ float obuf[128 * G];

  const int tid = threadIdx.x;
  const int lane = tid & 63;
  const int wv = tid >> 6;       // wave 0..3
  const int qd = lane >> 4;      // quad 0..3
  const int col = lane & 15;
  const int pair0 = blockIdx.x * G;
  const int b = pair0 >> 10;
  const int sbase = pair0 & 1023;

  // ---- build register-resident B-fragments (once per block) ----
  h8 bf1[3], bf2[2], bf3[2][2];
  {
    const int o1 = wv * 16 + col;  // L1/L2 channel for this lane
#pragma unroll
    for (int t = 0; t < 3; ++t) {
#pragma unroll
      for (int j = 0; j < 8; ++j) {
        int kp = t * 32 + qd * 8 + j;  // permuted K index
        float v = 0.f;
        if (kp < 64) v = w0[o1 * 67 + 3 + kp];
        else if (kp < 67) v = w0[o1 * 67 + (kp - 64)];
        bf1[t][j] = (_Float16)v;
      }
    }
#pragma unroll
    for (int t = 0; t < 2; ++t) {
#pragma unroll
      for (int j = 0; j < 8; ++j) {
        int k = t * 32 + qd * 8 + j;
        bf2[t][j] = (_Float16)w1[o1 * 64 + k];
      }
    }
#pragma unroll
    for (int u = 0; u < 2; ++u) {
      const int o3 = (wv + 4 * u) * 16 + col;
#pragma unroll
      for (int t = 0; t < 2; ++t) {
#pragma unroll
        for (int j = 0; j < 8; ++j) {
          int k = t * 32 + qd * 8 + j;
          bf3[u][t][j] = (_Float16)w2[o3 * 64 + k];
        }
      }
    }
  }
  const int o12 = wv * 16 + col;
  const float sA = s0[o12], bA = b0[o12];
  const float sB = s1[o12], bB = b1[o12];
  const float sC0 = s2[o12], bC0 = b2[o12];
  const float sC1 = s2[o12 + 64], bC1 = b2[o12 + 64];

  for (int t = tid; t < 32 * 40; t += 256) {
    x0[(t / 40) * 104 + 64 + (t % 40)] = (_Float16)0.f;
  }

  const int gn = tid >> 3, gk = tid & 7;

  f4 pf0, pf1;
  float pxr = 0.f, pyr = 0.f, pzr = 0.f, cxr = 0.f, cyr = 0.f, czr = 0.f;
  {
    const int pid = idxin[pair0 * NSAMPLE + gn];
    const float* fr = feat + ((size_t)(b * NPTS) + pid) * NCH + gk * 8;
    pf0 = *(const f4*)fr;
    pf1 = *(const f4*)(fr + 4);
    if (gk == 0) {
      const float* pr = xyz + ((size_t)(b * NPTS) + pid) * 3;
      pxr = pr[0]; pyr = pr[1]; pzr = pr[2];
      cxr = newxyz[pair0 * 3 + 0];
      cyr = newxyz[pair0 * 3 + 1];
      czr = newxyz[pair0 * 3 + 2];
    }
  }

  for (int g = 0; g < G; ++g) {
    {
      h8 hv;
#pragma unroll
      for (int q = 0; q < 4; ++q) {
        hv[q] = (_Float16)pf0[q];
        hv[4 + q] = (_Float16)pf1[q];
      }
      *(h8*)&x0[gn * 104 + gk * 8] = hv;
      if (gk == 0) {
        x0[gn * 104 + 64] = (_Float16)(pxr - cxr);
        x0[gn * 104 + 65] = (_Float16)(pyr - cyr);
        x0[gn * 104 + 66] = (_Float16)(pzr - czr);
      }
    }
    __syncthreads();  // bar A: x0 ready

    if (g + 1 < G) {
      const int pairg = pair0 + g + 1;
      const int pid = idxin[pairg * NSAMPLE + gn];
      const float* fr = feat + ((size_t)(b * NPTS) + pid) * NCH + gk * 8;
      pf0 = *(const f4*)fr;
      pf1 = *(const f4*)(fr + 4);
      if (gk == 0) {
        const float* pr = xyz + ((size_t)(b * NPTS) + pid) * 3;
        pxr = pr[0]; pyr = pr[1]; pzr = pr[2];
        cxr = newxyz[pairg * 3 + 0];
        cyr = newxyz[pairg * 3 + 1];
        czr = newxyz[pairg * 3 + 2];
      }
    }

    // ---- layer 1 ----
    {
      f4 a0 = {0.f, 0.f, 0.f, 0.f}, a1 = a0;
#pragma unroll
      for (int t = 0; t < 3; ++t) {
        h8 fa0 = *(const h8*)&x0[col * 104 + t * 32 + qd * 8];
        h8 fa1 = *(const h8*)&x0[(16 + col) * 104 + t * 32 + qd * 8];
        a0 = __builtin_amdgcn_mfma_f32_16x16x32_f16(fa0, bf1[t], a0, 0, 0, 0);
        a1 = __builtin_amdgcn_mfma_f32_16x16x32_f16(fa1, bf1[t], a1, 0, 0, 0);
      }
#pragma unroll
      for (int r = 0; r < 4; ++r) {
        float v0 = fmaxf(fmaf(a0[r], sA, bA), 0.f);
        float v1 = fmaxf(fmaf(a1[r], sA, bA), 0.f);
        x1[(qd * 4 + r) * 72 + o12] = (_Float16)v0;
        x1[(16 + qd * 4 + r) * 72 + o12] = (_Float16)v1;
      }
    }
    __syncthreads();  // bar B: x1 ready

    // ---- layer 2 ----
    {
      f4 a0 = {0.f, 0.f, 0.f, 0.f}, a1 = a0;
#pragma unroll
      for (int t = 0; t < 2; ++t) {
        h8 fa0 = *(const h8*)&x1[col * 72 + t * 32 + qd * 8];
        h8 fa1 = *(const h8*)&x1[(16 + col) * 72 + t * 32 + qd * 8];
        a0 = __builtin_amdgcn_mfma_f32_16x16x32_f16(fa0, bf2[t], a0, 0, 0, 0);
        a1 = __builtin_amdgcn_mfma_f32_16x16x32_f16(fa1, bf2[t], a1, 0, 0, 0);
      }
#pragma unroll
      for (int r = 0; r < 4; ++r) {
        float v0 = fmaxf(fmaf(a0[r], sB, bB), 0.f);
        float v1 = fmaxf(fmaf(a1[r], sB, bB), 0.f);
        x2[(qd * 4 + r) * 72 + o12] = (_Float16)v0;
        x2[(16 + qd * 4 + r) * 72 + o12] = (_Float16)v1;
      }
    }
    __syncthreads();  // bar C: x2 ready

    // ---- layer 3 + max-pool ----
    {
      f4 c00 = {0.f, 0.f, 0.f, 0.f}, c01 = c00, c10 = c00, c11 = c00;
#pragma unroll
      for (int t = 0; t < 2; ++t) {
        h8 fa0 = *(const h8*)&x2[col * 72 + t * 32 + qd * 8];
        h8 fa1 = *(const h8*)&x2[(16 + col) * 72 + t * 32 + qd * 8];
        c00 = __builtin_amdgcn_mfma_f32_16x16x32_f16(fa0, bf3[0][t], c00, 0, 0, 0);
        c01 = __builtin_amdgcn_mfma_f32_16x16x32_f16(fa1, bf3[0][t], c01, 0, 0, 0);
        c10 = __builtin_amdgcn_mfma_f32_16x16x32_f16(fa0, bf3[1][t], c10, 0, 0, 0);
        c11 = __builtin_amdgcn_mfma_f32_16x16x32_f16(fa1, bf3[1][t], c11, 0, 0, 0);
      }
      float mx0 = 0.f, mx1 = 0.f;  // relu output >= 0
#pragma unroll
      for (int r = 0; r < 4; ++r) {
        mx0 = fmaxf(mx0, fmaxf(fmaf(c00[r], sC0, bC0), 0.f));
        mx0 = fmaxf(mx0, fmaxf(fmaf(c01[r], sC0, bC0), 0.f));
        mx1 = fmaxf(mx1, fmaxf(fmaf(c10[r], sC1, bC1), 0.f));
        mx1 = fmaxf(mx1, fmaxf(fmaf(c11[r], sC1, bC1), 0.f));
      }
      mx0 = fmaxf(mx0, __shfl_xor(mx0, 16));
      mx0 = fmaxf(mx0, __shfl_xor(mx0, 32));
      mx1 = fmaxf(mx1, __shfl_xor(mx1, 16));
      mx1 = fmaxf(mx1, __shfl_xor(mx1, 32));
      if (lane < 16) {
        obuf[o12 * G + g] = mx0;
        obuf[(o12 + 64) * G + g] = mx1;
      }
    }
  }

  __syncthreads();
  {
    const int ch = tid >> 1, hb = (tid & 1) * 8;
    f4 v0 = *(const f4*)&obuf[ch * G + hb];
    f4 v1 = *(const f4*)&obuf[ch * G + hb + 4];
    float* dst = &outf[((size_t)(b * 128 + ch)) * 1024 + sbase + hb];
    *(f4*)dst = v0;
    *(f4*)(dst + 4) = v1;
  }
}

extern "C" void kernel_launch(void* const* d_in, const int* in_sizes, int n_in,
                              void* d_out, int out_size, void* d_ws, size_t ws_size,
                              hipStream_t stream) {
  const float* xyz = (const float*)d_in[0];
  const float* feat = (const float*)d_in[1];
  const float* w0 = (const float*)d_in[2];
  const float* s0 = (const float*)d_in[3];
  const float* b0 = (const float*)d_in[4];
  const float* w1 = (const float*)d_in[5];
  const float* s1 = (const float*)d_in[6];
  const float* b1 = (const float*)d_in[7];
  const float* w2 = (const float*)d_in[8];
  const float* s2 = (const float*)d_in[9];
  const float* b2 = (const float*)d_in[10];

  float* newxyz = (float*)d_out;                    // (8,1024,3)
  float* outf = (float*)d_out + BATCH * NPOINT * 3; // (8,128,1024)
  int* idxws = (int*)d_ws;                          // (8*1024, 32) ints = 1 MB
  // FPS sync records reuse the idx workspace (free until ball_kernel runs):
  // u64 rec[BATCH][2][SUBS] = 1 KB at d_ws base. Zero tags each launch.
  unsigned long long* rec = (unsigned long long*)d_ws;

  hipMemsetAsync(d_ws, 0, BATCH * 2 * SUBS * sizeof(unsigned long long), stream);
  fps_kernel<<<BATCH * SUBS, 64, 0, stream>>>(xyz, newxyz, rec);
  ball_kernel<<<(BATCH * NPOINT) / 4, 256, 0, stream>>>(xyz, newxyz, idxws);
  group_mlp_kernel<<<(BATCH * NPOINT) / G, 256, 0, stream>>>(
      xyz, feat, w0, s0, b0, w1, s1, b1, w2, s2, b2, idxws, newxyz, outf);
}

// Round 6
// 1143.726 us; speedup vs baseline: 1.2296x; 1.2296x over previous
//
#include <hip/hip_runtime.h>

#define BATCH 8
#define NPTS 8192
#define NCH 64
#define NPOINT 1024
#define NSAMPLE 32
#define G 16  // groups per MLP block

typedef float f4 __attribute__((ext_vector_type(4)));
typedef float f2 __attribute__((ext_vector_type(2)));
typedef _Float16 h8 __attribute__((ext_vector_type(8)));

// DPP-based u64 max step: merge with the value DPP-shifted across lanes.
template <int CTRL>
__device__ __forceinline__ unsigned long long dpp_max_u64(unsigned long long k) {
  int lo = (int)(unsigned int)k;
  int hi = (int)(unsigned int)(k >> 32);
  int slo = __builtin_amdgcn_update_dpp(lo, lo, CTRL, 0xf, 0xf, false);
  int shi = __builtin_amdgcn_update_dpp(hi, hi, CTRL, 0xf, 0xf, false);
  unsigned long long s =
      ((unsigned long long)(unsigned int)shi << 32) | (unsigned int)slo;
  return (s > k) ? s : k;
}

// ---------------------------------------------------------------------------
// Furthest point sampling — R17: revert to the R2 structure (fps 921us: 256
// thr / 16 f2 per thread / slim key-only merge; R16's multi-CU sync cost
// ~1500cy/iter > compute saved, steady 1264us + 31ms cold outlier).
// New in R17: force packed-f32 arithmetic. VALUBusy arithmetic says the f2
// distance update is scalarized (~20 instr/slot); gfx950 has VOP3P
// v_pk_add_f32 / v_pk_mul_f32 (no pk min/max f32) which hipcc never emits
// from f2 source. Inline-asm pk ops cut the update to ~12 instr/slot
// (-256 issue cyc/iter on the critical SIMD); 4-way tmax accumulators cut
// the 16-deep dependent fmax chain (~-60 cyc dep latency). Bitwise-exact:
// pk add/mul are IEEE-identical per element, a-b == a+(-b) exactly, the
// ((dx^2+dy^2)+dz^2) order is kept, fmax reassociation is exact (no
// rounding, no NaNs), mind updates + serial scan unchanged -> identical
// selection. Predict fps 921 -> ~790-840; if unchanged, compiler already
// packed and the residual is stall-bound.
// ---------------------------------------------------------------------------
__global__ __launch_bounds__(256, 1) void fps_kernel(
    const float* __restrict__ xyz, float* __restrict__ newxyz) {
  const int b = blockIdx.x;
  const int tid = threadIdx.x;
  const int lane = tid & 63;
  const int wid = tid >> 6;  // 0..3
  const float* xb = xyz + (size_t)b * NPTS * 3;

  __shared__ float px_l[NPTS], py_l[NPTS], pz_l[NPTS];   // 96 KB SoA
  __shared__ __align__(16) unsigned long long pk2[2][4]; // key per wave
  __shared__ unsigned short winidx[NPOINT];

  // coalesced global -> LDS staging
  for (int p = tid; p < NPTS; p += 256) {
    px_l[p] = xb[p * 3 + 0];
    py_l[p] = xb[p * 3 + 1];
    pz_l[p] = xb[p * 3 + 2];
  }
  __syncthreads();

  // register fill from LDS: thread owns pairs (2t+512j, 2t+512j+1)
  f2 pxv[16], pyv[16], pzv[16], mindv[16];
#pragma unroll
  for (int j = 0; j < 16; ++j) {
    int p = 2 * tid + 512 * j;
    pxv[j] = *(const f2*)&px_l[p];
    pyv[j] = *(const f2*)&py_l[p];
    pzv[j] = *(const f2*)&pz_l[p];
    mindv[j] = f2{1e10f, 1e10f};
  }
  // pin coordinates into VGPRs (R13: keeps them opaque / resident)
#pragma unroll
  for (int j = 0; j < 16; ++j) {
    asm volatile("" : "+v"(pxv[j]), "+v"(pyv[j]), "+v"(pzv[j]));
  }
  float qx = px_l[0], qy = py_l[0], qz = pz_l[0];  // pivot = point 0

  for (int i = 1; i < NPOINT; ++i) {
#pragma clang fp contract(off)
    const int par = i & 1;
    // negated pivot splat: a - q == a + (-q) exactly (sign flip is exact)
    f2 nqx2 = f2{-qx, -qx}, nqy2 = f2{-qy, -qy}, nqz2 = f2{-qz, -qz};

    // distance update via packed f32 VOP3P (exact ref order), min update,
    // and 4 independent max accumulators (fmax reassociation is exact).
    f2 tacc0 = f2{0.f, 0.f}, tacc1 = tacc0, tacc2 = tacc0, tacc3 = tacc0;
#pragma unroll
    for (int j = 0; j < 16; ++j) {
      f2 dx, dy, dz, xx, yy, zz, s1, d;
      asm("v_pk_add_f32 %0, %1, %2" : "=v"(dx) : "v"(pxv[j]), "v"(nqx2));
      asm("v_pk_add_f32 %0, %1, %2" : "=v"(dy) : "v"(pyv[j]), "v"(nqy2));
      asm("v_pk_add_f32 %0, %1, %2" : "=v"(dz) : "v"(pzv[j]), "v"(nqz2));
      asm("v_pk_mul_f32 %0, %1, %1" : "=v"(xx) : "v"(dx));
      asm("v_pk_mul_f32 %0, %1, %1" : "=v"(yy) : "v"(dy));
      asm("v_pk_mul_f32 %0, %1, %1" : "=v"(zz) : "v"(dz));
      asm("v_pk_add_f32 %0, %1, %2" : "=v"(s1) : "v"(xx), "v"(yy));
      asm("v_pk_add_f32 %0, %1, %2" : "=v"(d) : "v"(s1), "v"(zz));
      f2 m = __builtin_elementwise_min(mindv[j], d);
      mindv[j] = m;
      if ((j & 3) == 0) tacc0 = __builtin_elementwise_max(tacc0, m);
      if ((j & 3) == 1) tacc1 = __builtin_elementwise_max(tacc1, m);
      if ((j & 3) == 2) tacc2 = __builtin_elementwise_max(tacc2, m);
      if ((j & 3) == 3) tacc3 = __builtin_elementwise_max(tacc3, m);
    }
    f2 t01 = __builtin_elementwise_max(tacc0, tacc1);
    f2 t23 = __builtin_elementwise_max(tacc2, tacc3);
    f2 tmax = __builtin_elementwise_max(t01, t23);
    float lmax = fmaxf(tmax.x, tmax.y);  // minds >= 0, so 0-init is safe

    // thread-local lowest global index achieving lmax (proven serial form)
    // global idx = 2*tid + 512*j + k; scan j desc, y(k=1) then x(k=0)
    int c = 0;
#pragma unroll
    for (int j = 15; j >= 0; --j) {
      if (mindv[j].y == lmax) c = 2 * j + 1;
      if (mindv[j].x == lmax) c = 2 * j;
    }
    unsigned int gidx = (unsigned int)(2 * tid + ((c >> 1) << 9) + (c & 1));
    unsigned long long key =
        ((unsigned long long)__float_as_uint(lmax) << 32) |
        (unsigned long long)(~gidx);

    // wave argmax via DPP (VALU-speed), result valid in lane 63
    key = dpp_max_u64<0x111>(key);  // row_shr:1
    key = dpp_max_u64<0x112>(key);  // row_shr:2
    key = dpp_max_u64<0x114>(key);  // row_shr:4
    key = dpp_max_u64<0x118>(key);  // row_shr:8
    key = dpp_max_u64<0x142>(key);  // row_bcast:15
    key = dpp_max_u64<0x143>(key);  // row_bcast:31

    if (lane == 63) pk2[par][wid] = key;  // 8B only
    __syncthreads();

    // merge 4 keys: 2x ds_read_b128 + 3 u64 compare-selects
    ulonglong2 k01 = *(const ulonglong2*)&pk2[par][0];
    ulonglong2 k23 = *(const ulonglong2*)&pk2[par][2];
    unsigned long long m01 = (k01.x > k01.y) ? k01.x : k01.y;
    unsigned long long m23 = (k23.x > k23.y) ? k23.x : k23.y;
    unsigned long long mk = (m01 > m23) ? m01 : m23;
    unsigned int widx = ~(unsigned int)mk;  // identical on every thread

    // pivot coords: broadcast ds_read at the winner (post-merge, parallel)
    qx = px_l[widx];
    qy = py_l[widx];
    qz = pz_l[widx];
    if (tid == 0) winidx[i] = (unsigned short)widx;
  }

  __syncthreads();
  // write all 1024 sampled points from LDS
  for (int t = tid; t < NPOINT; t += 256) {
    const int idx = (t == 0) ? 0 : (int)winidx[t];
    float* op = newxyz + b * (NPOINT * 3) + t * 3;
    op[0] = px_l[idx];
    op[1] = py_l[idx];
    op[2] = pz_l[idx];
  }
}

// ---------------------------------------------------------------------------
// Ball query: one wave per (b, s) center. Unchanged (exact fp32).
// ---------------------------------------------------------------------------
__global__ __launch_bounds__(256) void ball_kernel(const float* __restrict__ xyz,
                                                   const float* __restrict__ newxyz,
                                                   int* __restrict__ idxout) {
  const int lane = threadIdx.x & 63;
  const int pair = blockIdx.x * 4 + (threadIdx.x >> 6);
  const int b = pair >> 10;
  const float cx = newxyz[pair * 3 + 0];
  const float cy = newxyz[pair * 3 + 1];
  const float cz = newxyz[pair * 3 + 2];
  const float* xb = xyz + (size_t)b * NPTS * 3;
  int* op = idxout + pair * NSAMPLE;

  int cnt = 0;
  int first = 0;
  for (int base = 0; base < NPTS && cnt < NSAMPLE; base += 64) {
    const int p = base + lane;
    const float* pp = xb + p * 3;
    float dx = __fsub_rn(cx, pp[0]);
    float dy = __fsub_rn(cy, pp[1]);
    float dz = __fsub_rn(cz, pp[2]);
    float d2 = __fadd_rn(__fadd_rn(__fmul_rn(dx, dx), __fmul_rn(dy, dy)),
                         __fmul_rn(dz, dz));
    bool pred = d2 < 0.04f;
    unsigned long long m = __ballot(pred);
    if (cnt == 0 && m) first = base + __builtin_ctzll(m);
    int rank = cnt + (int)__popcll(m & ((1ull << lane) - 1ull));
    if (pred && rank < NSAMPLE) op[rank] = p;
    cnt += (int)__popcll(m);
  }
  if (cnt < NSAMPLE) {
    for (int r = cnt + lane; r < NSAMPLE; r += 64) op[r] = first;
  }
}

// ---------------------------------------------------------------------------
// Group + 3-layer MLP + max-pool via f16 MFMA. G=16 groups/block, grid 512.
// Unchanged from R10 (weights register-resident as B-fragments, layouts
// HW-verified m89/m120, fp32 accumulate; absmax 0.0156 < 0.054).
// ---------------------------------------------------------------------------
__global__ __launch_bounds__(256) void group_mlp_kernel(
    const float* __restrict__ xyz, const float* __restrict__ feat,
    const float* __restrict__ w0, const float* __restrict__ s0, const float* __restrict__ b0,
    const float* __restrict__ w1, const float* __restrict__ s1, const float* __restrict__ b1,
    const float* __restrict__ w2, const float* __restrict__ s2, const float* __restrict__ b2,
    const int* __restrict__ idxin, const float* __restrict__ newxyz,
    float* __restrict__ outf) {
  __shared__ _Float16 x0[32 * 104];  // layer1 input, K-padded to 96
  __shared__ _Float16 x1[32 * 72];   // layer2 input
  __shared__ _Float16 x2[32 * 72];   // layer3 input
  __shared__ float obuf[128 * G];

  const int tid = threadIdx.x;
  const int lane = tid & 63;
  const int wv = tid >> 6;       // wave 0..3
  const int qd = lane >> 4;      // quad 0..3
  const int col = lane & 15;
  const int pair0 = blockIdx.x * G;
  const int b = pair0 >> 10;
  const int sbase = pair0 & 1023;

  // ---- build register-resident B-fragments (once per block) ----
  h8 bf1[3], bf2[2], bf3[2][2];
  {
    const int o1 = wv * 16 + col;  // L1/L2 channel for this lane
#pragma unroll
    for (int t = 0; t < 3; ++t) {
#pragma unroll
      for (int j = 0; j < 8; ++j) {
        int kp = t * 32 + qd * 8 + j;  // permuted K index
        float v = 0.f;
        if (kp < 64) v = w0[o1 * 67 + 3 + kp];
        else if (kp < 67) v = w0[o1 * 67 + (kp - 64)];
        bf1[t][j] = (_Float16)v;
      }
    }
#pragma unroll
    for (int t = 0; t < 2; ++t) {
#pragma unroll
      for (int j = 0; j < 8; ++j) {
        int k = t * 32 + qd * 8 + j;
        bf2[t][j] = (_Float16)w1[o1 * 64 + k];
      }
    }
#pragma unroll
    for (int u = 0; u < 2; ++u) {
      const int o3 = (wv + 4 * u) * 16 + col;
#pragma unroll
      for (int t = 0; t < 2; ++t) {
#pragma unroll
        for (int j = 0; j < 8; ++j) {
          int k = t * 32 + qd * 8 + j;
          bf3[u][t][j] = (_Float16)w2[o3 * 64 + k];
        }
      }
    }
  }
  const int o12 = wv * 16 + col;
  const float sA = s0[o12], bA = b0[o12];
  const float sB = s1[o12], bB = b1[o12];
  const float sC0 = s2[o12], bC0 = b2[o12];
  const float sC1 = s2[o12 + 64], bC1 = b2[o12 + 64];

  for (int t = tid; t < 32 * 40; t += 256) {
    x0[(t / 40) * 104 + 64 + (t % 40)] = (_Float16)0.f;
  }

  const int gn = tid >> 3, gk = tid & 7;

  f4 pf0, pf1;
  float pxr = 0.f, pyr = 0.f, pzr = 0.f, cxr = 0.f, cyr = 0.f, czr = 0.f;
  {
    const int pid = idxin[pair0 * NSAMPLE + gn];
    const float* fr = feat + ((size_t)(b * NPTS) + pid) * NCH + gk * 8;
    pf0 = *(const f4*)fr;
    pf1 = *(const f4*)(fr + 4);
    if (gk == 0) {
      const float* pr = xyz + ((size_t)(b * NPTS) + pid) * 3;
      pxr = pr[0]; pyr = pr[1]; pzr = pr[2];
      cxr = newxyz[pair0 * 3 + 0];
      cyr = newxyz[pair0 * 3 + 1];
      czr = newxyz[pair0 * 3 + 2];
    }
  }

  for (int g = 0; g < G; ++g) {
    {
      h8 hv;
#pragma unroll
      for (int q = 0; q < 4; ++q) {
        hv[q] = (_Float16)pf0[q];
        hv[4 + q] = (_Float16)pf1[q];
      }
      *(h8*)&x0[gn * 104 + gk * 8] = hv;
      if (gk == 0) {
        x0[gn * 104 + 64] = (_Float16)(pxr - cxr);
        x0[gn * 104 + 65] = (_Float16)(pyr - cyr);
        x0[gn * 104 + 66] = (_Float16)(pzr - czr);
      }
    }
    __syncthreads();  // bar A: x0 ready

    if (g + 1 < G) {
      const int pairg = pair0 + g + 1;
      const int pid = idxin[pairg * NSAMPLE + gn];
      const float* fr = feat + ((size_t)(b * NPTS) + pid) * NCH + gk * 8;
      pf0 = *(const f4*)fr;
      pf1 = *(const f4*)(fr + 4);
      if (gk == 0) {
        const float* pr = xyz + ((size_t)(b * NPTS) + pid) * 3;
        pxr = pr[0]; pyr = pr[1]; pzr = pr[2];
        cxr = newxyz[pairg * 3 + 0];
        cyr = newxyz[pairg * 3 + 1];
        czr = newxyz[pairg * 3 + 2];
      }
    }

    // ---- layer 1 ----
    {
      f4 a0 = {0.f, 0.f, 0.f, 0.f}, a1 = a0;
#pragma unroll
      for (int t = 0; t < 3; ++t) {
        h8 fa0 = *(const h8*)&x0[col * 104 + t * 32 + qd * 8];
        h8 fa1 = *(const h8*)&x0[(16 + col) * 104 + t * 32 + qd * 8];
        a0 = __builtin_amdgcn_mfma_f32_16x16x32_f16(fa0, bf1[t], a0, 0, 0, 0);
        a1 = __builtin_amdgcn_mfma_f32_16x16x32_f16(fa1, bf1[t], a1, 0, 0, 0);
      }
#pragma unroll
      for (int r = 0; r < 4; ++r) {
        float v0 = fmaxf(fmaf(a0[r], sA, bA), 0.f);
        float v1 = fmaxf(fmaf(a1[r], sA, bA), 0.f);
        x1[(qd * 4 + r) * 72 + o12] = (_Float16)v0;
        x1[(16 + qd * 4 + r) * 72 + o12] = (_Float16)v1;
      }
    }
    __syncthreads();  // bar B: x1 ready

    // ---- layer 2 ----
    {
      f4 a0 = {0.f, 0.f, 0.f, 0.f}, a1 = a0;
#pragma unroll
      for (int t = 0; t < 2; ++t) {
        h8 fa0 = *(const h8*)&x1[col * 72 + t * 32 + qd * 8];
        h8 fa1 = *(const h8*)&x1[(16 + col) * 72 + t * 32 + qd * 8];
        a0 = __builtin_amdgcn_mfma_f32_16x16x32_f16(fa0, bf2[t], a0, 0, 0, 0);
        a1 = __builtin_amdgcn_mfma_f32_16x16x32_f16(fa1, bf2[t], a1, 0, 0, 0);
      }
#pragma unroll
      for (int r = 0; r < 4; ++r) {
        float v0 = fmaxf(fmaf(a0[r], sB, bB), 0.f);
        float v1 = fmaxf(fmaf(a1[r], sB, bB), 0.f);
        x2[(qd * 4 + r) * 72 + o12] = (_Float16)v0;
        x2[(16 + qd * 4 + r) * 72 + o12] = (_Float16)v1;
      }
    }
    __syncthreads();  // bar C: x2 ready

    // ---- layer 3 + max-pool ----
    {
      f4 c00 = {0.f, 0.f, 0.f, 0.f}, c01 = c00, c10 = c00, c11 = c00;
#pragma unroll
      for (int t = 0; t < 2; ++t) {
        h8 fa0 = *(const h8*)&x2[col * 72 + t * 32 + qd * 8];
        h8 fa1 = *(const h8*)&x2[(16 + col) * 72 + t * 32 + qd * 8];
        c00 = __builtin_amdgcn_mfma_f32_16x16x32_f16(fa0, bf3[0][t], c00, 0, 0, 0);
        c01 = __builtin_amdgcn_mfma_f32_16x16x32_f16(fa1, bf3[0][t], c01, 0, 0, 0);
        c10 = __builtin_amdgcn_mfma_f32_16x16x32_f16(fa0, bf3[1][t], c10, 0, 0, 0);
        c11 = __builtin_amdgcn_mfma_f32_16x16x32_f16(fa1, bf3[1][t], c11, 0, 0, 0);
      }
      float mx0 = 0.f, mx1 = 0.f;  // relu output >= 0
#pragma unroll
      for (int r = 0; r < 4; ++r) {
        mx0 = fmaxf(mx0, fmaxf(fmaf(c00[r], sC0, bC0), 0.f));
        mx0 = fmaxf(mx0, fmaxf(fmaf(c01[r], sC0, bC0), 0.f));
        mx1 = fmaxf(mx1, fmaxf(fmaf(c10[r], sC1, bC1), 0.f));
        mx1 = fmaxf(mx1, fmaxf(fmaf(c11[r], sC1, bC1), 0.f));
      }
      mx0 = fmaxf(mx0, __shfl_xor(mx0, 16));
      mx0 = fmaxf(mx0, __shfl_xor(mx0, 32));
      mx1 = fmaxf(mx1, __shfl_xor(mx1, 16));
      mx1 = fmaxf(mx1, __shfl_xor(mx1, 32));
      if (lane < 16) {
        obuf[o12 * G + g] = mx0;
        obuf[(o12 + 64) * G + g] = mx1;
      }
    }
  }

  __syncthreads();
  {
    const int ch = tid >> 1, hb = (tid & 1) * 8;
    f4 v0 = *(const f4*)&obuf[ch * G + hb];
    f4 v1 = *(const f4*)&obuf[ch * G + hb + 4];
    float* dst = &outf[((size_t)(b * 128 + ch)) * 1024 + sbase + hb];
    *(f4*)dst = v0;
    *(f4*)(dst + 4) = v1;
  }
}

extern "C" void kernel_launch(void* const* d_in, const int* in_sizes, int n_in,
                              void* d_out, int out_size, void* d_ws, size_t ws_size,
                              hipStream_t stream) {
  const float* xyz = (const float*)d_in[0];
  const float* feat = (const float*)d_in[1];
  const float* w0 = (const float*)d_in[2];
  const float* s0 = (const float*)d_in[3];
  const float* b0 = (const float*)d_in[4];
  const float* w1 = (const float*)d_in[5];
  const float* s1 = (const float*)d_in[6];
  const float* b1 = (const float*)d_in[7];
  const float* w2 = (const float*)d_in[8];
  const float* s2 = (const float*)d_in[9];
  const float* b2 = (const float*)d_in[10];

  float* newxyz = (float*)d_out;                    // (8,1024,3)
  float* outf = (float*)d_out + BATCH * NPOINT * 3; // (8,128,1024)
  int* idxws = (int*)d_ws;                          // (8*1024, 32) ints = 1 MB

  fps_kernel<<<BATCH, 256, 0, stream>>>(xyz, newxyz);
  ball_kernel<<<(BATCH * NPOINT) / 4, 256, 0, stream>>>(xyz, newxyz, idxws);
  group_mlp_kernel<<<(BATCH * NPOINT) / G, 256, 0, stream>>>(
      xyz, feat, w0, s0, b0, w1, s1, b1, w2, s2, b2, idxws, newxyz, outf);
}

// Round 7
// 1039.988 us; speedup vs baseline: 1.3523x; 1.0997x over previous
//
#include <hip/hip_runtime.h>

#define BATCH 8
#define NPTS 8192
#define NCH 64
#define NPOINT 1024
#define NSAMPLE 32
#define G 16  // groups per MLP block

typedef float f4 __attribute__((ext_vector_type(4)));
typedef float f2 __attribute__((ext_vector_type(2)));
typedef _Float16 h8 __attribute__((ext_vector_type(8)));

// DPP-based u32 max step: merge with the value DPP-shifted across lanes.
template <int CTRL>
__device__ __forceinline__ unsigned int dpp_max_u32(unsigned int k) {
  int s = __builtin_amdgcn_update_dpp((int)k, (int)k, CTRL, 0xf, 0xf, false);
  unsigned int u = (unsigned int)s;
  return (u > k) ? u : k;
}

// ---------------------------------------------------------------------------
// Furthest point sampling — R18: slim reduce path. R17's pk-asm regressed
// (VALU busy-cycles ROSE: compiler already packs f2 + folds neg modifiers;
// opaque asm defeats it) — reverted to plain C arithmetic. R12-R17 deltas fit
// an issue+latency model (~330 essential instr/iter + ~900cy serial chain);
// the only lever left is removing instrs AND chain depth together.
// Change: contiguous ownership (thread t owns [32t,32t+32)) makes global
// index order == (lane, slot) order, so the wave argmax needs only:
//   u32 value DPP max (6x2 instr vs u64's 6x5; dists>=+0 so f32 order ==
//   u32 bit order) -> readlane(63) -> ballot(lmax==wmax) -> ctz = lowest
//   matching lane == lowest-index holder (ref tie-break) -> serial scan
//   (proven form, vs wmax) -> readlane(winlane) for the index.
// Cross-wave merge keeps the u64 key (wmax<<32)|~gidx — unchanged semantics.
// 4-acc tmax tree: exact (fmax reassoc), -48cy dep, 0 extra instr.
// Predict fps 921 -> ~880-905; if >=915, reduce path isn't critical ->
// fps exhausted at this structure, pivot to ball/mlp tail.
// ---------------------------------------------------------------------------
__global__ __launch_bounds__(256, 1) void fps_kernel(
    const float* __restrict__ xyz, float* __restrict__ newxyz) {
  const int b = blockIdx.x;
  const int tid = threadIdx.x;
  const int lane = tid & 63;
  const int wid = tid >> 6;  // 0..3
  const float* xb = xyz + (size_t)b * NPTS * 3;

  __shared__ float px_l[NPTS], py_l[NPTS], pz_l[NPTS];   // 96 KB SoA
  __shared__ __align__(16) unsigned long long pk2[2][4]; // key per wave
  __shared__ unsigned short winidx[NPOINT];

  // coalesced global -> LDS staging
  for (int p = tid; p < NPTS; p += 256) {
    px_l[p] = xb[p * 3 + 0];
    py_l[p] = xb[p * 3 + 1];
    pz_l[p] = xb[p * 3 + 2];
  }
  __syncthreads();

  // register fill from LDS: thread owns CONTIGUOUS [tid*32, tid*32+32);
  // slot j covers local indices 2j (x) and 2j+1 (y).
  // (fill is 32-way bank-conflicted — one-time cost ~1us, irrelevant.)
  f2 pxv[16], pyv[16], pzv[16], mindv[16];
#pragma unroll
  for (int j = 0; j < 16; ++j) {
    int p = tid * 32 + 2 * j;
    pxv[j] = *(const f2*)&px_l[p];
    pyv[j] = *(const f2*)&py_l[p];
    pzv[j] = *(const f2*)&pz_l[p];
    mindv[j] = f2{1e10f, 1e10f};
  }
  // pin coordinates (R13: proven neutral, prevents LDS rematerialization)
#pragma unroll
  for (int j = 0; j < 16; ++j) {
    asm volatile("" : "+v"(pxv[j]), "+v"(pyv[j]), "+v"(pzv[j]));
  }
  float qx = px_l[0], qy = py_l[0], qz = pz_l[0];  // pivot = point 0

  for (int i = 1; i < NPOINT; ++i) {
#pragma clang fp contract(off)
    const int par = i & 1;
    f2 qx2 = f2{qx, qx}, qy2 = f2{qy, qy}, qz2 = f2{qz, qz};

    // distance update (exact ref order) + 4-acc value max tree (exact:
    // fmax reassociation never rounds; all values >= +0)
    f2 tacc0 = f2{0.f, 0.f}, tacc1 = tacc0, tacc2 = tacc0, tacc3 = tacc0;
#pragma unroll
    for (int j = 0; j < 16; ++j) {
      f2 dx = pxv[j] - qx2;
      f2 dy = pyv[j] - qy2;
      f2 dz = pzv[j] - qz2;
      f2 d = (dx * dx + dy * dy) + dz * dz;
      f2 m = __builtin_elementwise_min(mindv[j], d);
      mindv[j] = m;
      if ((j & 3) == 0) tacc0 = __builtin_elementwise_max(tacc0, m);
      if ((j & 3) == 1) tacc1 = __builtin_elementwise_max(tacc1, m);
      if ((j & 3) == 2) tacc2 = __builtin_elementwise_max(tacc2, m);
      if ((j & 3) == 3) tacc3 = __builtin_elementwise_max(tacc3, m);
    }
    f2 t01 = __builtin_elementwise_max(tacc0, tacc1);
    f2 t23 = __builtin_elementwise_max(tacc2, tacc3);
    f2 tmax = __builtin_elementwise_max(t01, t23);
    float lmax = fmaxf(tmax.x, tmax.y);

    // wave value-max via u32 DPP (dists >= +0: f32 order == u32 order)
    unsigned int kv = __float_as_uint(lmax);
    kv = dpp_max_u32<0x111>(kv);  // row_shr:1
    kv = dpp_max_u32<0x112>(kv);  // row_shr:2
    kv = dpp_max_u32<0x114>(kv);  // row_shr:4
    kv = dpp_max_u32<0x118>(kv);  // row_shr:8
    kv = dpp_max_u32<0x142>(kv);  // row_bcast:15
    kv = dpp_max_u32<0x143>(kv);  // row_bcast:31
    const unsigned int wmaxb =
        (unsigned int)__builtin_amdgcn_readlane((int)kv, 63);
    const float wmaxf = __uint_as_float(wmaxb);

    // lowest lane holding wmax == lowest-global-index holder (contiguous
    // ownership: lower lane -> strictly lower indices). Ref tie-break.
    unsigned long long mb = __ballot(lmax == wmaxf);
    const int winlane = (int)__builtin_ctzll(mb);

    // thread-local lowest matching local index (proven serial scan form):
    // scan j desc, y(k=1) then x(k=0) -> lowest 2j+k with mind == wmax
    int c = 0;
#pragma unroll
    for (int j = 15; j >= 0; --j) {
      if (mindv[j].y == wmaxf) c = 2 * j + 1;
      if (mindv[j].x == wmaxf) c = 2 * j;
    }
    unsigned int gidx = (unsigned int)(tid * 32 + c);
    const unsigned int wgidx =
        (unsigned int)__builtin_amdgcn_readlane((int)gidx, winlane);

    // per-wave key (uniform): same format as before -> merge unchanged
    unsigned long long key =
        ((unsigned long long)wmaxb << 32) | (unsigned long long)(~wgidx);

    if (lane == 63) pk2[par][wid] = key;  // 8B only
    __syncthreads();

    // merge 4 keys: 2x ds_read_b128 + 3 u64 compare-selects
    ulonglong2 k01 = *(const ulonglong2*)&pk2[par][0];
    ulonglong2 k23 = *(const ulonglong2*)&pk2[par][2];
    unsigned long long m01 = (k01.x > k01.y) ? k01.x : k01.y;
    unsigned long long m23 = (k23.x > k23.y) ? k23.x : k23.y;
    unsigned long long mk = (m01 > m23) ? m01 : m23;
    unsigned int widx = ~(unsigned int)mk;  // identical on every thread

    // pivot coords: broadcast ds_read at the winner (post-merge, parallel)
    qx = px_l[widx];
    qy = py_l[widx];
    qz = pz_l[widx];
    if (tid == 0) winidx[i] = (unsigned short)widx;
  }

  __syncthreads();
  // write all 1024 sampled points from LDS
  for (int t = tid; t < NPOINT; t += 256) {
    const int idx = (t == 0) ? 0 : (int)winidx[t];
    float* op = newxyz + b * (NPOINT * 3) + t * 3;
    op[0] = px_l[idx];
    op[1] = py_l[idx];
    op[2] = pz_l[idx];
  }
}

// ---------------------------------------------------------------------------
// Ball query: one wave per (b, s) center. Unchanged (exact fp32).
// ---------------------------------------------------------------------------
__global__ __launch_bounds__(256) void ball_kernel(const float* __restrict__ xyz,
                                                   const float* __restrict__ newxyz,
                                                   int* __restrict__ idxout) {
  const int lane = threadIdx.x & 63;
  const int pair = blockIdx.x * 4 + (threadIdx.x >> 6);
  const int b = pair >> 10;
  const float cx = newxyz[pair * 3 + 0];
  const float cy = newxyz[pair * 3 + 1];
  const float cz = newxyz[pair * 3 + 2];
  const float* xb = xyz + (size_t)b * NPTS * 3;
  int* op = idxout + pair * NSAMPLE;

  int cnt = 0;
  int first = 0;
  for (int base = 0; base < NPTS && cnt < NSAMPLE; base += 64) {
    const int p = base + lane;
    const float* pp = xb + p * 3;
    float dx = __fsub_rn(cx, pp[0]);
    float dy = __fsub_rn(cy, pp[1]);
    float dz = __fsub_rn(cz, pp[2]);
    float d2 = __fadd_rn(__fadd_rn(__fmul_rn(dx, dx), __fmul_rn(dy, dy)),
                         __fmul_rn(dz, dz));
    bool pred = d2 < 0.04f;
    unsigned long long m = __ballot(pred);
    if (cnt == 0 && m) first = base + __builtin_ctzll(m);
    int rank = cnt + (int)__popcll(m & ((1ull << lane) - 1ull));
    if (pred && rank < NSAMPLE) op[rank] = p;
    cnt += (int)__popcll(m);
  }
  if (cnt < NSAMPLE) {
    for (int r = cnt + lane; r < NSAMPLE; r += 64) op[r] = first;
  }
}

// ---------------------------------------------------------------------------
// Group + 3-layer MLP + max-pool via f16 MFMA. G=16 groups/block, grid 512.
// Unchanged from R10 (weights register-resident as B-fragments, layouts
// HW-verified m89/m120, fp32 accumulate; absmax 0.0156 < 0.054).
// ---------------------------------------------------------------------------
__global__ __launch_bounds__(256) void group_mlp_kernel(
    const float* __restrict__ xyz, const float* __restrict__ feat,
    const float* __restrict__ w0, const float* __restrict__ s0, const float* __restrict__ b0,
    const float* __restrict__ w1, const float* __restrict__ s1, const float* __restrict__ b1,
    const float* __restrict__ w2, const float* __restrict__ s2, const float* __restrict__ b2,
    const int* __restrict__ idxin, const float* __restrict__ newxyz,
    float* __restrict__ outf) {
  __shared__ _Float16 x0[32 * 104];  // layer1 input, K-padded to 96
  __shared__ _Float16 x1[32 * 72];   // layer2 input
  __shared__ _Float16 x2[32 * 72];   // layer3 input
  __shared__ float obuf[128 * G];

  const int tid = threadIdx.x;
  const int lane = tid & 63;
  const int wv = tid >> 6;       // wave 0..3
  const int qd = lane >> 4;      // quad 0..3
  const int col = lane & 15;
  const int pair0 = blockIdx.x * G;
  const int b = pair0 >> 10;
  const int sbase = pair0 & 1023;

  // ---- build register-resident B-fragments (once per block) ----
  h8 bf1[3], bf2[2], bf3[2][2];
  {
    const int o1 = wv * 16 + col;  // L1/L2 channel for this lane
#pragma unroll
    for (int t = 0; t < 3; ++t) {
#pragma unroll
      for (int j = 0; j < 8; ++j) {
        int kp = t * 32 + qd * 8 + j;  // permuted K index
        float v = 0.f;
        if (kp < 64) v = w0[o1 * 67 + 3 + kp];
        else if (kp < 67) v = w0[o1 * 67 + (kp - 64)];
        bf1[t][j] = (_Float16)v;
      }
    }
#pragma unroll
    for (int t = 0; t < 2; ++t) {
#pragma unroll
      for (int j = 0; j < 8; ++j) {
        int k = t * 32 + qd * 8 + j;
        bf2[t][j] = (_Float16)w1[o1 * 64 + k];
      }
    }
#pragma unroll
    for (int u = 0; u < 2; ++u) {
      const int o3 = (wv + 4 * u) * 16 + col;
#pragma unroll
      for (int t = 0; t < 2; ++t) {
#pragma unroll
        for (int j = 0; j < 8; ++j) {
          int k = t * 32 + qd * 8 + j;
          bf3[u][t][j] = (_Float16)w2[o3 * 64 + k];
        }
      }
    }
  }
  const int o12 = wv * 16 + col;
  const float sA = s0[o12], bA = b0[o12];
  const float sB = s1[o12], bB = b1[o12];
  const float sC0 = s2[o12], bC0 = b2[o12];
  const float sC1 = s2[o12 + 64], bC1 = b2[o12 + 64];

  for (int t = tid; t < 32 * 40; t += 256) {
    x0[(t / 40) * 104 + 64 + (t % 40)] = (_Float16)0.f;
  }

  const int gn = tid >> 3, gk = tid & 7;

  f4 pf0, pf1;
  float pxr = 0.f, pyr = 0.f, pzr = 0.f, cxr = 0.f, cyr = 0.f, czr = 0.f;
  {
    const int pid = idxin[pair0 * NSAMPLE + gn];
    const float* fr = feat + ((size_t)(b * NPTS) + pid) * NCH + gk * 8;
    pf0 = *(const f4*)fr;
    pf1 = *(const f4*)(fr + 4);
    if (gk == 0) {
      const float* pr = xyz + ((size_t)(b * NPTS) + pid) * 3;
      pxr = pr[0]; pyr = pr[1]; pzr = pr[2];
      cxr = newxyz[pair0 * 3 + 0];
      cyr = newxyz[pair0 * 3 + 1];
      czr = newxyz[pair0 * 3 + 2];
    }
  }

  for (int g = 0; g < G; ++g) {
    {
      h8 hv;
#pragma unroll
      for (int q = 0; q < 4; ++q) {
        hv[q] = (_Float16)pf0[q];
        hv[4 + q] = (_Float16)pf1[q];
      }
      *(h8*)&x0[gn * 104 + gk * 8] = hv;
      if (gk == 0) {
        x0[gn * 104 + 64] = (_Float16)(pxr - cxr);
        x0[gn * 104 + 65] = (_Float16)(pyr - cyr);
        x0[gn * 104 + 66] = (_Float16)(pzr - czr);
      }
    }
    __syncthreads();  // bar A: x0 ready

    if (g + 1 < G) {
      const int pairg = pair0 + g + 1;
      const int pid = idxin[pairg * NSAMPLE + gn];
      const float* fr = feat + ((size_t)(b * NPTS) + pid) * NCH + gk * 8;
      pf0 = *(const f4*)fr;
      pf1 = *(const f4*)(fr + 4);
      if (gk == 0) {
        const float* pr = xyz + ((size_t)(b * NPTS) + pid) * 3;
        pxr = pr[0]; pyr = pr[1]; pzr = pr[2];
        cxr = newxyz[pairg * 3 + 0];
        cyr = newxyz[pairg * 3 + 1];
        czr = newxyz[pairg * 3 + 2];
      }
    }

    // ---- layer 1 ----
    {
      f4 a0 = {0.f, 0.f, 0.f, 0.f}, a1 = a0;
#pragma unroll
      for (int t = 0; t < 3; ++t) {
        h8 fa0 = *(const h8*)&x0[col * 104 + t * 32 + qd * 8];
        h8 fa1 = *(const h8*)&x0[(16 + col) * 104 + t * 32 + qd * 8];
        a0 = __builtin_amdgcn_mfma_f32_16x16x32_f16(fa0, bf1[t], a0, 0, 0, 0);
        a1 = __builtin_amdgcn_mfma_f32_16x16x32_f16(fa1, bf1[t], a1, 0, 0, 0);
      }
#pragma unroll
      for (int r = 0; r < 4; ++r) {
        float v0 = fmaxf(fmaf(a0[r], sA, bA), 0.f);
        float v1 = fmaxf(fmaf(a1[r], sA, bA), 0.f);
        x1[(qd * 4 + r) * 72 + o12] = (_Float16)v0;
        x1[(16 + qd * 4 + r) * 72 + o12] = (_Float16)v1;
      }
    }
    __syncthreads();  // bar B: x1 ready

    // ---- layer 2 ----
    {
      f4 a0 = {0.f, 0.f, 0.f, 0.f}, a1 = a0;
#pragma unroll
      for (int t = 0; t < 2; ++t) {
        h8 fa0 = *(const h8*)&x1[col * 72 + t * 32 + qd * 8];
        h8 fa1 = *(const h8*)&x1[(16 + col) * 72 + t * 32 + qd * 8];
        a0 = __builtin_amdgcn_mfma_f32_16x16x32_f16(fa0, bf2[t], a0, 0, 0, 0);
        a1 = __builtin_amdgcn_mfma_f32_16x16x32_f16(fa1, bf2[t], a1, 0, 0, 0);
      }
#pragma unroll
      for (int r = 0; r < 4; ++r) {
        float v0 = fmaxf(fmaf(a0[r], sB, bB), 0.f);
        float v1 = fmaxf(fmaf(a1[r], sB, bB), 0.f);
        x2[(qd * 4 + r) * 72 + o12] = (_Float16)v0;
        x2[(16 + qd * 4 + r) * 72 + o12] = (_Float16)v1;
      }
    }
    __syncthreads();  // bar C: x2 ready

    // ---- layer 3 + max-pool ----
    {
      f4 c00 = {0.f, 0.f, 0.f, 0.f}, c01 = c00, c10 = c00, c11 = c00;
#pragma unroll
      for (int t = 0; t < 2; ++t) {
        h8 fa0 = *(const h8*)&x2[col * 72 + t * 32 + qd * 8];
        h8 fa1 = *(const h8*)&x2[(16 + col) * 72 + t * 32 + qd * 8];
        c00 = __builtin_amdgcn_mfma_f32_16x16x32_f16(fa0, bf3[0][t], c00, 0, 0, 0);
        c01 = __builtin_amdgcn_mfma_f32_16x16x32_f16(fa1, bf3[0][t], c01, 0, 0, 0);
        c10 = __builtin_amdgcn_mfma_f32_16x16x32_f16(fa0, bf3[1][t], c10, 0, 0, 0);
        c11 = __builtin_amdgcn_mfma_f32_16x16x32_f16(fa1, bf3[1][t], c11, 0, 0, 0);
      }
      float mx0 = 0.f, mx1 = 0.f;  // relu output >= 0
#pragma unroll
      for (int r = 0; r < 4; ++r) {
        mx0 = fmaxf(mx0, fmaxf(fmaf(c00[r], sC0, bC0), 0.f));
        mx0 = fmaxf(mx0, fmaxf(fmaf(c01[r], sC0, bC0), 0.f));
        mx1 = fmaxf(mx1, fmaxf(fmaf(c10[r], sC1, bC1), 0.f));
        mx1 = fmaxf(mx1, fmaxf(fmaf(c11[r], sC1, bC1), 0.f));
      }
      mx0 = fmaxf(mx0, __shfl_xor(mx0, 16));
      mx0 = fmaxf(mx0, __shfl_xor(mx0, 32));
      mx1 = fmaxf(mx1, __shfl_xor(mx1, 16));
      mx1 = fmaxf(mx1, __shfl_xor(mx1, 32));
      if (lane < 16) {
        obuf[o12 * G + g] = mx0;
        obuf[(o12 + 64) * G + g] = mx1;
      }
    }
  }

  __syncthreads();
  {
    const int ch = tid >> 1, hb = (tid & 1) * 8;
    f4 v0 = *(const f4*)&obuf[ch * G + hb];
    f4 v1 = *(const f4*)&obuf[ch * G + hb + 4];
    float* dst = &outf[((size_t)(b * 128 + ch)) * 1024 + sbase + hb];
    *(f4*)dst = v0;
    *(f4*)(dst + 4) = v1;
  }
}

extern "C" void kernel_launch(void* const* d_in, const int* in_sizes, int n_in,
                              void* d_out, int out_size, void* d_ws, size_t ws_size,
                              hipStream_t stream) {
  const float* xyz = (const float*)d_in[0];
  const float* feat = (const float*)d_in[1];
  const float* w0 = (const float*)d_in[2];
  const float* s0 = (const float*)d_in[3];
  const float* b0 = (const float*)d_in[4];
  const float* w1 = (const float*)d_in[5];
  const float* s1 = (const float*)d_in[6];
  const float* b1 = (const float*)d_in[7];
  const float* w2 = (const float*)d_in[8];
  const float* s2 = (const float*)d_in[9];
  const float* b2 = (const float*)d_in[10];

  float* newxyz = (float*)d_out;                    // (8,1024,3)
  float* outf = (float*)d_out + BATCH * NPOINT * 3; // (8,128,1024)
  int* idxws = (int*)d_ws;                          // (8*1024, 32) ints = 1 MB

  fps_kernel<<<BATCH, 256, 0, stream>>>(xyz, newxyz);
  ball_kernel<<<(BATCH * NPOINT) / 4, 256, 0, stream>>>(xyz, newxyz, idxws);
  group_mlp_kernel<<<(BATCH * NPOINT) / G, 256, 0, stream>>>(
      xyz, feat, w0, s0, b0, w1, s1, b1, w2, s2, b2, idxws, newxyz, outf);
}

// Round 8
// 982.648 us; speedup vs baseline: 1.4312x; 1.0584x over previous
//
#include <hip/hip_runtime.h>

#define BATCH 8
#define NPTS 8192
#define NCH 64
#define NPOINT 1024
#define NSAMPLE 32
#define G 16  // groups per MLP block

typedef float f4 __attribute__((ext_vector_type(4)));
typedef float f2 __attribute__((ext_vector_type(2)));
typedef _Float16 h8 __attribute__((ext_vector_type(8)));

// DPP-based u32 max step: merge with the value DPP-shifted across lanes.
template <int CTRL>
__device__ __forceinline__ unsigned int dpp_max_u32(unsigned int k) {
  int s = __builtin_amdgcn_update_dpp((int)k, (int)k, CTRL, 0xf, 0xf, false);
  unsigned int u = (unsigned int)s;
  return (u > k) ? u : k;
}

// ---------------------------------------------------------------------------
// Furthest point sampling — R19. R18 (contiguous ownership + u32 DPP) was the
// first confirmed win (921->891, predicted 880-905): removing instrs AND
// chain depth together pays ~0.85ns/instr + chain savings. Two more cuts of
// the same profile, zero added instructions:
//  (1) scan moved BEFORE the DPP reduce, comparing thread-local lmax instead
//      of wmaxf. For the winning lane lmax==wmax, so readlane(gidx, winlane)
//      is unchanged — but the 32-step dependent cndmask chain (~190cy) is now
//      independent of the DPP chain and interleaves with its stalls instead
//      of following readlane(wmax) on the critical path.
//  (2) per-slot max-accumulate via fmaxf(fmaxf(acc,m.x),m.y) -> clang fuses
//      v_max3_f32 (source-level, folding preserved — R17's asm lesson):
//      1 instr/slot instead of 2. Exact (max never rounds, >=+0).
// Selection bitwise identical to ref (min-update order untouched; lowest-
// index tie-break preserved at lane and wave level; merge key unchanged).
// Predict fps 891 -> ~815-855; if >=880, reorder didn't absorb -> pivot to
// ball/mlp tail next.
// ---------------------------------------------------------------------------
__global__ __launch_bounds__(256, 1) void fps_kernel(
    const float* __restrict__ xyz, float* __restrict__ newxyz) {
  const int b = blockIdx.x;
  const int tid = threadIdx.x;
  const int lane = tid & 63;
  const int wid = tid >> 6;  // 0..3
  const float* xb = xyz + (size_t)b * NPTS * 3;

  __shared__ float px_l[NPTS], py_l[NPTS], pz_l[NPTS];   // 96 KB SoA
  __shared__ __align__(16) unsigned long long pk2[2][4]; // key per wave
  __shared__ unsigned short winidx[NPOINT];

  // coalesced global -> LDS staging
  for (int p = tid; p < NPTS; p += 256) {
    px_l[p] = xb[p * 3 + 0];
    py_l[p] = xb[p * 3 + 1];
    pz_l[p] = xb[p * 3 + 2];
  }
  __syncthreads();

  // register fill from LDS: thread owns CONTIGUOUS [tid*32, tid*32+32);
  // slot j covers local indices 2j (x) and 2j+1 (y).
  // (fill is 32-way bank-conflicted — one-time ~1us, measured harmless R18.)
  f2 pxv[16], pyv[16], pzv[16], mindv[16];
#pragma unroll
  for (int j = 0; j < 16; ++j) {
    int p = tid * 32 + 2 * j;
    pxv[j] = *(const f2*)&px_l[p];
    pyv[j] = *(const f2*)&py_l[p];
    pzv[j] = *(const f2*)&pz_l[p];
    mindv[j] = f2{1e10f, 1e10f};
  }
  // pin coordinates (R13: proven neutral, prevents LDS rematerialization)
#pragma unroll
  for (int j = 0; j < 16; ++j) {
    asm volatile("" : "+v"(pxv[j]), "+v"(pyv[j]), "+v"(pzv[j]));
  }
  float qx = px_l[0], qy = py_l[0], qz = pz_l[0];  // pivot = point 0

  for (int i = 1; i < NPOINT; ++i) {
#pragma clang fp contract(off)
    const int par = i & 1;
    f2 qx2 = f2{qx, qx}, qy2 = f2{qy, qy}, qz2 = f2{qz, qz};

    // distance update (exact ref order); max-accumulate via max3 fusion
    // (exact: fmax reassociation never rounds; all values >= +0)
    float tm0 = 0.f, tm1 = 0.f, tm2 = 0.f, tm3 = 0.f;
#pragma unroll
    for (int j = 0; j < 16; ++j) {
      f2 dx = pxv[j] - qx2;
      f2 dy = pyv[j] - qy2;
      f2 dz = pzv[j] - qz2;
      f2 d = (dx * dx + dy * dy) + dz * dz;
      f2 m = __builtin_elementwise_min(mindv[j], d);
      mindv[j] = m;
      if ((j & 3) == 0) tm0 = fmaxf(fmaxf(tm0, m.x), m.y);
      if ((j & 3) == 1) tm1 = fmaxf(fmaxf(tm1, m.x), m.y);
      if ((j & 3) == 2) tm2 = fmaxf(fmaxf(tm2, m.x), m.y);
      if ((j & 3) == 3) tm3 = fmaxf(fmaxf(tm3, m.x), m.y);
    }
    const float lmax = fmaxf(fmaxf(tm0, tm1), fmaxf(tm2, tm3));

    // thread-local lowest matching local index vs LMAX (proven serial scan
    // form), placed BEFORE the DPP reduce: independent of wmax, so it
    // overlaps the DPP chain. For the winning lane lmax==wmax -> same c.
    int c = 0;
#pragma unroll
    for (int j = 15; j >= 0; --j) {
      if (mindv[j].y == lmax) c = 2 * j + 1;
      if (mindv[j].x == lmax) c = 2 * j;
    }
    const unsigned int gidx = (unsigned int)(tid * 32 + c);

    // wave value-max via u32 DPP (dists >= +0: f32 order == u32 order)
    unsigned int kv = __float_as_uint(lmax);
    kv = dpp_max_u32<0x111>(kv);  // row_shr:1
    kv = dpp_max_u32<0x112>(kv);  // row_shr:2
    kv = dpp_max_u32<0x114>(kv);  // row_shr:4
    kv = dpp_max_u32<0x118>(kv);  // row_shr:8
    kv = dpp_max_u32<0x142>(kv);  // row_bcast:15
    kv = dpp_max_u32<0x143>(kv);  // row_bcast:31
    const unsigned int wmaxb =
        (unsigned int)__builtin_amdgcn_readlane((int)kv, 63);
    const float wmaxf = __uint_as_float(wmaxb);

    // lowest lane holding wmax == lowest-global-index holder (contiguous
    // ownership: lower lane -> strictly lower indices). Ref tie-break.
    unsigned long long mb = __ballot(lmax == wmaxf);
    const int winlane = (int)__builtin_ctzll(mb);
    const unsigned int wgidx =
        (unsigned int)__builtin_amdgcn_readlane((int)gidx, winlane);

    // per-wave key (uniform): same format as before -> merge unchanged
    unsigned long long key =
        ((unsigned long long)wmaxb << 32) | (unsigned long long)(~wgidx);

    if (lane == 63) pk2[par][wid] = key;  // 8B only
    __syncthreads();

    // merge 4 keys: 2x ds_read_b128 + 3 u64 compare-selects
    ulonglong2 k01 = *(const ulonglong2*)&pk2[par][0];
    ulonglong2 k23 = *(const ulonglong2*)&pk2[par][2];
    unsigned long long m01 = (k01.x > k01.y) ? k01.x : k01.y;
    unsigned long long m23 = (k23.x > k23.y) ? k23.x : k23.y;
    unsigned long long mk = (m01 > m23) ? m01 : m23;
    unsigned int widx = ~(unsigned int)mk;  // identical on every thread

    // pivot coords: broadcast ds_read at the winner (post-merge, parallel)
    qx = px_l[widx];
    qy = py_l[widx];
    qz = pz_l[widx];
    if (tid == 0) winidx[i] = (unsigned short)widx;
  }

  __syncthreads();
  // write all 1024 sampled points from LDS
  for (int t = tid; t < NPOINT; t += 256) {
    const int idx = (t == 0) ? 0 : (int)winidx[t];
    float* op = newxyz + b * (NPOINT * 3) + t * 3;
    op[0] = px_l[idx];
    op[1] = py_l[idx];
    op[2] = pz_l[idx];
  }
}

// ---------------------------------------------------------------------------
// Ball query: one wave per (b, s) center. Unchanged (exact fp32).
// ---------------------------------------------------------------------------
__global__ __launch_bounds__(256) void ball_kernel(const float* __restrict__ xyz,
                                                   const float* __restrict__ newxyz,
                                                   int* __restrict__ idxout) {
  const int lane = threadIdx.x & 63;
  const int pair = blockIdx.x * 4 + (threadIdx.x >> 6);
  const int b = pair >> 10;
  const float cx = newxyz[pair * 3 + 0];
  const float cy = newxyz[pair * 3 + 1];
  const float cz = newxyz[pair * 3 + 2];
  const float* xb = xyz + (size_t)b * NPTS * 3;
  int* op = idxout + pair * NSAMPLE;

  int cnt = 0;
  int first = 0;
  for (int base = 0; base < NPTS && cnt < NSAMPLE; base += 64) {
    const int p = base + lane;
    const float* pp = xb + p * 3;
    float dx = __fsub_rn(cx, pp[0]);
    float dy = __fsub_rn(cy, pp[1]);
    float dz = __fsub_rn(cz, pp[2]);
    float d2 = __fadd_rn(__fadd_rn(__fmul_rn(dx, dx), __fmul_rn(dy, dy)),
                         __fmul_rn(dz, dz));
    bool pred = d2 < 0.04f;
    unsigned long long m = __ballot(pred);
    if (cnt == 0 && m) first = base + __builtin_ctzll(m);
    int rank = cnt + (int)__popcll(m & ((1ull << lane) - 1ull));
    if (pred && rank < NSAMPLE) op[rank] = p;
    cnt += (int)__popcll(m);
  }
  if (cnt < NSAMPLE) {
    for (int r = cnt + lane; r < NSAMPLE; r += 64) op[r] = first;
  }
}

// ---------------------------------------------------------------------------
// Group + 3-layer MLP + max-pool via f16 MFMA. G=16 groups/block, grid 512.
// Unchanged from R10 (weights register-resident as B-fragments, layouts
// HW-verified m89/m120, fp32 accumulate; absmax 0.0156 < 0.054).
// ---------------------------------------------------------------------------
__global__ __launch_bounds__(256) void group_mlp_kernel(
    const float* __restrict__ xyz, const float* __restrict__ feat,
    const float* __restrict__ w0, const float* __restrict__ s0, const float* __restrict__ b0,
    const float* __restrict__ w1, const float* __restrict__ s1, const float* __restrict__ b1,
    const float* __restrict__ w2, const float* __restrict__ s2, const float* __restrict__ b2,
    const int* __restrict__ idxin, const float* __restrict__ newxyz,
    float* __restrict__ outf) {
  __shared__ _Float16 x0[32 * 104];  // layer1 input, K-padded to 96
  __shared__ _Float16 x1[32 * 72];   // layer2 input
  __shared__ _Float16 x2[32 * 72];   // layer3 input
  __shared__ float obuf[128 * G];

  const int tid = threadIdx.x;
  const int lane = tid & 63;
  const int wv = tid >> 6;       // wave 0..3
  const int qd = lane >> 4;      // quad 0..3
  const int col = lane & 15;
  const int pair0 = blockIdx.x * G;
  const int b = pair0 >> 10;
  const int sbase = pair0 & 1023;

  // ---- build register-resident B-fragments (once per block) ----
  h8 bf1[3], bf2[2], bf3[2][2];
  {
    const int o1 = wv * 16 + col;  // L1/L2 channel for this lane
#pragma unroll
    for (int t = 0; t < 3; ++t) {
#pragma unroll
      for (int j = 0; j < 8; ++j) {
        int kp = t * 32 + qd * 8 + j;  // permuted K index
        float v = 0.f;
        if (kp < 64) v = w0[o1 * 67 + 3 + kp];
        else if (kp < 67) v = w0[o1 * 67 + (kp - 64)];
        bf1[t][j] = (_Float16)v;
      }
    }
#pragma unroll
    for (int t = 0; t < 2; ++t) {
#pragma unroll
      for (int j = 0; j < 8; ++j) {
        int k = t * 32 + qd * 8 + j;
        bf2[t][j] = (_Float16)w1[o1 * 64 + k];
      }
    }
#pragma unroll
    for (int u = 0; u < 2; ++u) {
      const int o3 = (wv + 4 * u) * 16 + col;
#pragma unroll
      for (int t = 0; t < 2; ++t) {
#pragma unroll
        for (int j = 0; j < 8; ++j) {
          int k = t * 32 + qd * 8 + j;
          bf3[u][t][j] = (_Float16)w2[o3 * 64 + k];
        }
      }
    }
  }
  const int o12 = wv * 16 + col;
  const float sA = s0[o12], bA = b0[o12];
  const float sB = s1[o12], bB = b1[o12];
  const float sC0 = s2[o12], bC0 = b2[o12];
  const float sC1 = s2[o12 + 64], bC1 = b2[o12 + 64];

  for (int t = tid; t < 32 * 40; t += 256) {
    x0[(t / 40) * 104 + 64 + (t % 40)] = (_Float16)0.f;
  }

  const int gn = tid >> 3, gk = tid & 7;

  f4 pf0, pf1;
  float pxr = 0.f, pyr = 0.f, pzr = 0.f, cxr = 0.f, cyr = 0.f, czr = 0.f;
  {
    const int pid = idxin[pair0 * NSAMPLE + gn];
    const float* fr = feat + ((size_t)(b * NPTS) + pid) * NCH + gk * 8;
    pf0 = *(const f4*)fr;
    pf1 = *(const f4*)(fr + 4);
    if (gk == 0) {
      const float* pr = xyz + ((size_t)(b * NPTS) + pid) * 3;
      pxr = pr[0]; pyr = pr[1]; pzr = pr[2];
      cxr = newxyz[pair0 * 3 + 0];
      cyr = newxyz[pair0 * 3 + 1];
      czr = newxyz[pair0 * 3 + 2];
    }
  }

  for (int g = 0; g < G; ++g) {
    {
      h8 hv;
#pragma unroll
      for (int q = 0; q < 4; ++q) {
        hv[q] = (_Float16)pf0[q];
        hv[4 + q] = (_Float16)pf1[q];
      }
      *(h8*)&x0[gn * 104 + gk * 8] = hv;
      if (gk == 0) {
        x0[gn * 104 + 64] = (_Float16)(pxr - cxr);
        x0[gn * 104 + 65] = (_Float16)(pyr - cyr);
        x0[gn * 104 + 66] = (_Float16)(pzr - czr);
      }
    }
    __syncthreads();  // bar A: x0 ready

    if (g + 1 < G) {
      const int pairg = pair0 + g + 1;
      const int pid = idxin[pairg * NSAMPLE + gn];
      const float* fr = feat + ((size_t)(b * NPTS) + pid) * NCH + gk * 8;
      pf0 = *(const f4*)fr;
      pf1 = *(const f4*)(fr + 4);
      if (gk == 0) {
        const float* pr = xyz + ((size_t)(b * NPTS) + pid) * 3;
        pxr = pr[0]; pyr = pr[1]; pzr = pr[2];
        cxr = newxyz[pairg * 3 + 0];
        cyr = newxyz[pairg * 3 + 1];
        czr = newxyz[pairg * 3 + 2];
      }
    }

    // ---- layer 1 ----
    {
      f4 a0 = {0.f, 0.f, 0.f, 0.f}, a1 = a0;
#pragma unroll
      for (int t = 0; t < 3; ++t) {
        h8 fa0 = *(const h8*)&x0[col * 104 + t * 32 + qd * 8];
        h8 fa1 = *(const h8*)&x0[(16 + col) * 104 + t * 32 + qd * 8];
        a0 = __builtin_amdgcn_mfma_f32_16x16x32_f16(fa0, bf1[t], a0, 0, 0, 0);
        a1 = __builtin_amdgcn_mfma_f32_16x16x32_f16(fa1, bf1[t], a1, 0, 0, 0);
      }
#pragma unroll
      for (int r = 0; r < 4; ++r) {
        float v0 = fmaxf(fmaf(a0[r], sA, bA), 0.f);
        float v1 = fmaxf(fmaf(a1[r], sA, bA), 0.f);
        x1[(qd * 4 + r) * 72 + o12] = (_Float16)v0;
        x1[(16 + qd * 4 + r) * 72 + o12] = (_Float16)v1;
      }
    }
    __syncthreads();  // bar B: x1 ready

    // ---- layer 2 ----
    {
      f4 a0 = {0.f, 0.f, 0.f, 0.f}, a1 = a0;
#pragma unroll
      for (int t = 0; t < 2; ++t) {
        h8 fa0 = *(const h8*)&x1[col * 72 + t * 32 + qd * 8];
        h8 fa1 = *(const h8*)&x1[(16 + col) * 72 + t * 32 + qd * 8];
        a0 = __builtin_amdgcn_mfma_f32_16x16x32_f16(fa0, bf2[t], a0, 0, 0, 0);
        a1 = __builtin_amdgcn_mfma_f32_16x16x32_f16(fa1, bf2[t], a1, 0, 0, 0);
      }
#pragma unroll
      for (int r = 0; r < 4; ++r) {
        float v0 = fmaxf(fmaf(a0[r], sB, bB), 0.f);
        float v1 = fmaxf(fmaf(a1[r], sB, bB), 0.f);
        x2[(qd * 4 + r) * 72 + o12] = (_Float16)v0;
        x2[(16 + qd * 4 + r) * 72 + o12] = (_Float16)v1;
      }
    }
    __syncthreads();  // bar C: x2 ready

    // ---- layer 3 + max-pool ----
    {
      f4 c00 = {0.f, 0.f, 0.f, 0.f}, c01 = c00, c10 = c00, c11 = c00;
#pragma unroll
      for (int t = 0; t < 2; ++t) {
        h8 fa0 = *(const h8*)&x2[col * 72 + t * 32 + qd * 8];
        h8 fa1 = *(const h8*)&x2[(16 + col) * 72 + t * 32 + qd * 8];
        c00 = __builtin_amdgcn_mfma_f32_16x16x32_f16(fa0, bf3[0][t], c00, 0, 0, 0);
        c01 = __builtin_amdgcn_mfma_f32_16x16x32_f16(fa1, bf3[0][t], c01, 0, 0, 0);
        c10 = __builtin_amdgcn_mfma_f32_16x16x32_f16(fa0, bf3[1][t], c10, 0, 0, 0);
        c11 = __builtin_amdgcn_mfma_f32_16x16x32_f16(fa1, bf3[1][t], c11, 0, 0, 0);
      }
      float mx0 = 0.f, mx1 = 0.f;  // relu output >= 0
#pragma unroll
      for (int r = 0; r < 4; ++r) {
        mx0 = fmaxf(mx0, fmaxf(fmaf(c00[r], sC0, bC0), 0.f));
        mx0 = fmaxf(mx0, fmaxf(fmaf(c01[r], sC0, bC0), 0.f));
        mx1 = fmaxf(mx1, fmaxf(fmaf(c10[r], sC1, bC1), 0.f));
        mx1 = fmaxf(mx1, fmaxf(fmaf(c11[r], sC1, bC1), 0.f));
      }
      mx0 = fmaxf(mx0, __shfl_xor(mx0, 16));
      mx0 = fmaxf(mx0, __shfl_xor(mx0, 32));
      mx1 = fmaxf(mx1, __shfl_xor(mx1, 16));
      mx1 = fmaxf(mx1, __shfl_xor(mx1, 32));
      if (lane < 16) {
        obuf[o12 * G + g] = mx0;
        obuf[(o12 + 64) * G + g] = mx1;
      }
    }
  }

  __syncthreads();
  {
    const int ch = tid >> 1, hb = (tid & 1) * 8;
    f4 v0 = *(const f4*)&obuf[ch * G + hb];
    f4 v1 = *(const f4*)&obuf[ch * G + hb + 4];
    float* dst = &outf[((size_t)(b * 128 + ch)) * 1024 + sbase + hb];
    *(f4*)dst = v0;
    *(f4*)(dst + 4) = v1;
  }
}

extern "C" void kernel_launch(void* const* d_in, const int* in_sizes, int n_in,
                              void* d_out, int out_size, void* d_ws, size_t ws_size,
                              hipStream_t stream) {
  const float* xyz = (const float*)d_in[0];
  const float* feat = (const float*)d_in[1];
  const float* w0 = (const float*)d_in[2];
  const float* s0 = (const float*)d_in[3];
  const float* b0 = (const float*)d_in[4];
  const float* w1 = (const float*)d_in[5];
  const float* s1 = (const float*)d_in[6];
  const float* b1 = (const float*)d_in[7];
  const float* w2 = (const float*)d_in[8];
  const float* s2 = (const float*)d_in[9];
  const float* b2 = (const float*)d_in[10];

  float* newxyz = (float*)d_out;                    // (8,1024,3)
  float* outf = (float*)d_out + BATCH * NPOINT * 3; // (8,128,1024)
  int* idxws = (int*)d_ws;                          // (8*1024, 32) ints = 1 MB

  fps_kernel<<<BATCH, 256, 0, stream>>>(xyz, newxyz);
  ball_kernel<<<(BATCH * NPOINT) / 4, 256, 0, stream>>>(xyz, newxyz, idxws);
  group_mlp_kernel<<<(BATCH * NPOINT) / G, 256, 0, stream>>>(
      xyz, feat, w0, s0, b0, w1, s1, b1, w2, s2, b2, idxws, newxyz, outf);
}